// Round 8
// baseline (282.986 us; speedup 1.0000x reference)
//
#include <hip/hip_runtime.h>
#include <math.h>

// SSIM loss fp32, B=64 H=W=512, 11x11 Gaussian sigma=1.5, separable (w ⊗ w).
// R16 = R14 resubmit #2. Infra failures are content-uncorrelated: R11's
// byte-identical source failed twice (R3,R4) then passed (R5); broker I/O in
// passing rounds shows push_in_npz_s up to 1320s (timeout-adjacent). R14
// audited 3x: ring algebra re-derived correct (slot i%11 accumulates h-rows
// i-10..i with w[i-j]=w[j-i+10] by symmetry); no hang paths (fixed trips, no
// cross-wave deps); no OOB (LDS max idx 73<80, partial wid<4096).
// R14: barrier-free per-wave streaming rewrite.
// R11/R13 post-mortem: stride-48 "conflict fix" landed but SQ_LDS_BANK_CONFLICT
// stayed 22-23M and dur only 136->130us -> conflicts were NOT dominant. VALUBusy
// pinned ~41% = structural ceiling: LDS 37.9KB caps 4 blocks/CU (16/32 waves) and
// each block idles ~88% at the 2 __syncthreads + LDS round-trips.
// R14 design: each WAVE owns a 64col x 64row output segment, streams 74 rows:
//   prefetch global row r+1 -> h-conv row r from per-wave LDS row buffer
//   (11 stride-1 b32 reads/array: 2 lanes/bank = free) -> 11-deep REGISTER ring
//   of v-conv partials (ring idx (U+d)%11 static via 11-step unrolled groups)
//   -> 1 SSIM emission/row/lane. No __syncthreads anywhere; wave self-syncs via
//   s_waitcnt lgkmcnt(0) + sched_barrier(0) (cross-lane LDS reuse is invisible
//   to per-thread alias analysis -> must fence explicitly).
// LDS 5376B/block, grid 4096 waves (16/CU). All 64 lanes emit valid outputs.

#define NPART 4096

struct W11 { float w[11]; };

__global__ __launch_bounds__(256, 4) void ssim_main(
    const float* __restrict__ x, const float* __restrict__ y,
    float* __restrict__ partial, W11 wk, int atomic_mode)
{
    // per-wave double-buffered row window: [wave][parity][arr(x,y)][74 cols pad 80]
    __shared__ float rbuf[4][2][2][80];          // 5120 B

    const int tid = threadIdx.x;
    const int l   = tid & 63;
    const int w   = tid >> 6;
    const int wid = (int)blockIdx.x * 4 + w;     // 0..4095
    const int seg   = wid & 7;                   // row segment
    const int strip = (wid >> 3) & 7;            // col strip
    const int z     = wid >> 6;                  // image
    const int C0 = strip << 6;
    const int R0 = seg << 6;
    const float* __restrict__ xb = x + (size_t)z * (512 * 512);
    const float* __restrict__ yb = y + (size_t)z * (512 * 512);

    // per-lane column geometry (constant over the march)
    // main: raw col C0-5+l (window slot l); tail lanes 54..63 also cover
    // slots 64..73 = cols C0+59..C0+68.
    const int   ca  = C0 - 5 + l;
    const float cma = ((unsigned)ca < 512u) ? 1.f : 0.f;
    const int   cac = min(max(ca, 0), 511);
    const bool  tl  = (l >= 54);
    const int   cb  = C0 + 5 + l;
    const float cmb = ((unsigned)cb < 512u) ? 1.f : 0.f;
    const int   cbc = min(max(cb, 0), 511);

    // v-conv register rings (all indices compile-time static)
    float accx[11], accy[11], accss[11], accxy[11];
    #pragma unroll
    for (int k = 0; k < 11; ++k) {
        accx[k] = 0.f; accy[k] = 0.f; accss[k] = 0.f; accxy[k] = 0.f;
    }
    float lsum = 0.f;

    // ---- prologue: load h-row R0-5 into parity 0 ----
    {
        const int hr = R0 - 5;
        float xa = 0.f, ya = 0.f, xt = 0.f, yt = 0.f;
        if ((unsigned)hr < 512u) {
            const int off = hr * 512;
            xa = xb[off + cac] * cma;
            ya = yb[off + cac] * cma;
            if (tl) { xt = xb[off + cbc] * cmb; yt = yb[off + cbc] * cmb; }
        }
        rbuf[w][0][0][l] = xa;
        rbuf[w][0][1][l] = ya;
        if (tl) { rbuf[w][0][0][l + 10] = xt; rbuf[w][0][1][l + 10] = yt; }
    }
    asm volatile("s_waitcnt lgkmcnt(0)" ::: "memory");
    __builtin_amdgcn_sched_barrier(0);

    // ---- steady state: 7 groups x 11 steps (i = 0..76; rows R0-5..R0+71) ----
    // step i: prefetch global row R0-4+i; consume h-row R0-5+i from parity i&1;
    // ring-accumulate; emit output row R0-10+i when 10 <= i <= 73; write
    // prefetched row to parity (i+1)&1; fence.
#define STEP(U, CBX, CBY, WBX, WBY)                                          \
    {                                                                        \
        const int i_  = 11 * g + (U);                                        \
        const int hrn = R0 - 4 + i_;                                         \
        float xa = 0.f, ya = 0.f, xt = 0.f, yt = 0.f;                        \
        if ((unsigned)hrn < 512u) {                                          \
            const int off = hrn * 512;                                       \
            xa = xb[off + cac] * cma;                                        \
            ya = yb[off + cac] * cma;                                        \
            if (tl) { xt = xb[off + cbc] * cmb; yt = yb[off + cbc] * cmb; }  \
        }                                                                    \
        float hx = 0.f, hy = 0.f, hss = 0.f, hxy = 0.f;                      \
        _Pragma("unroll")                                                    \
        for (int dd = 0; dd < 11; ++dd) {                                    \
            const float xs = (CBX)[l + dd];                                  \
            const float ys = (CBY)[l + dd];                                  \
            const float wd = wk.w[dd];                                       \
            hx  += wd * xs;                                                  \
            hy  += wd * ys;                                                  \
            hss += wd * (xs * xs + ys * ys);                                 \
            hxy += wd * (xs * ys);                                           \
        }                                                                    \
        _Pragma("unroll")                                                    \
        for (int dl = 0; dl < 11; ++dl) {                                    \
            const int s_ = ((U) + dl) % 11;                                  \
            const float wd = wk.w[dl];                                       \
            accx[s_]  += wd * hx;                                            \
            accy[s_]  += wd * hy;                                            \
            accss[s_] += wd * hss;                                           \
            accxy[s_] += wd * hxy;                                           \
        }                                                                    \
        if (i_ >= 10 && i_ <= 73) {                                          \
            const float mx  = accx[(U)], my = accy[(U)];                     \
            const float mx2 = mx * mx, my2 = my * my, mxy = mx * my;         \
            const float sgs = accss[(U)] - mx2 - my2;                        \
            const float sgx = accxy[(U)] - mxy;                              \
            const float num = (2.f * mxy + 1e-4f) * (2.f * sgx + 9e-4f);     \
            const float den = (mx2 + my2 + 1e-4f) * (sgs + 9e-4f) + 1e-12f;  \
            lsum += num * __builtin_amdgcn_rcpf(den);                        \
        }                                                                    \
        accx[(U)] = 0.f; accy[(U)] = 0.f; accss[(U)] = 0.f; accxy[(U)] = 0.f;\
        (WBX)[l] = xa; (WBY)[l] = ya;                                        \
        if (tl) { (WBX)[l + 10] = xt; (WBY)[l + 10] = yt; }                  \
        asm volatile("s_waitcnt lgkmcnt(0)" ::: "memory");                   \
        __builtin_amdgcn_sched_barrier(0);                                   \
    }

    #pragma unroll 1
    for (int g = 0; g < 7; ++g) {
        float* const bxA = rbuf[w][g & 1][0];        // parity for even-U consume
        float* const byA = rbuf[w][g & 1][1];
        float* const bxB = rbuf[w][(g & 1) ^ 1][0];
        float* const byB = rbuf[w][(g & 1) ^ 1][1];
        STEP(0,  bxA, byA, bxB, byB)
        STEP(1,  bxB, byB, bxA, byA)
        STEP(2,  bxA, byA, bxB, byB)
        STEP(3,  bxB, byB, bxA, byA)
        STEP(4,  bxA, byA, bxB, byB)
        STEP(5,  bxB, byB, bxA, byA)
        STEP(6,  bxA, byA, bxB, byB)
        STEP(7,  bxB, byB, bxA, byA)
        STEP(8,  bxA, byA, bxB, byB)
        STEP(9,  bxB, byB, bxA, byA)
        STEP(10, bxA, byA, bxB, byB)
    }
#undef STEP

    // ---- wave reduction (no cross-wave sync needed) ----
    #pragma unroll
    for (int off = 32; off; off >>= 1) lsum += __shfl_down(lsum, off);
    if (l == 0) {
        if (atomic_mode) atomicAdd(partial, lsum);
        else partial[wid] = lsum;
    }
}

__global__ __launch_bounds__(1024) void ssim_fin(const float* __restrict__ partial,
                                                 float* __restrict__ out, int n)
{
    float s = 0.f;
    for (int i = threadIdx.x; i < n; i += 1024) s += partial[i];
    #pragma unroll
    for (int off = 32; off; off >>= 1) s += __shfl_down(s, off);
    __shared__ float red[16];
    if ((threadIdx.x & 63) == 0) red[threadIdx.x >> 6] = s;
    __syncthreads();
    if (threadIdx.x == 0) {
        float v = 0.f;
        #pragma unroll
        for (int i = 0; i < 16; ++i) v += red[i];
        out[0] = 1.0f - v * (1.0f / 16777216.0f);
    }
}

extern "C" void kernel_launch(void* const* d_in, const int* in_sizes, int n_in,
                              void* d_out, int out_size, void* d_ws, size_t ws_size,
                              hipStream_t stream) {
    const float* x = (const float*)d_in[0];
    const float* y = (const float*)d_in[1];
    float* out = (float*)d_out;
    float* ws  = (float*)d_ws;

    W11 wk;
    double e[11], s = 0.0;
    for (int i = 0; i < 11; ++i) {
        double d = (double)i - 5.0;
        e[i] = exp(-(d * d) / 4.5);
        s += e[i];
    }
    for (int i = 0; i < 11; ++i) wk.w[i] = (float)(e[i] / s);

    const bool use_partial = ws_size >= (size_t)NPART * sizeof(float);
    if (!use_partial) hipMemsetAsync(d_ws, 0, sizeof(float), stream);

    hipLaunchKernelGGL(ssim_main, dim3(1024), dim3(256), 0, stream,
                       x, y, ws, wk, use_partial ? 0 : 1);
    hipLaunchKernelGGL(ssim_fin, dim3(1), dim3(1024), 0, stream,
                       ws, out, use_partial ? NPART : 1);
}